// Round 1
// baseline (100.229 us; speedup 1.0000x reference)
//
#include <hip/hip_runtime.h>
#include <math.h>

#define HOPSZ 551
#define LB   16            // output samples per thread
#define WU   48            // warm-up samples (C(51,3)*p_max^48 ~ 2.7e-3 envelope)
#define SPAN (LB + WU)     // 64 samples processed per thread
#define TPB  64            // one wave per block
#define BSPAN (TPB * LB)   // 1024 output samples per block
#define NROWS 8            // coefficient rows cached per block (need <= 5)
#define NQ   (SPAN / 4)    // 16 float4 loads per thread

// ---------------------------------------------------------------------------
// Single fused kernel:
//   phase 0: issue ALL x loads (16 x float4 + 2 history scalars) into
//     registers up front, so HBM latency overlaps phase-1 compute.
//   phase 1 (cooperative, one wave): compute NROWS hop-coefficient rows
//     (LFO -> 16-wide MLP -> p -> allpass cb[5]/cd[4]) into LDS; write p_out.
//   phase 2 (per-thread): warm-up + fused biquad -> TV-FIR -> LPC -> output,
//     entirely from registers.
// Exact piecewise-linear coeff interp: c(pos) = A + fr0*sA + relu(fr0-1)*sD,
// fr0 = pos - i0a; thread span (64 samples ~ 0.12 hop) crosses <= 1 knot.
// ---------------------------------------------------------------------------
__global__ __launch_bounds__(TPB) void k_fused(
    const float* __restrict__ x,
    const float* __restrict__ g1, const float* __restrict__ g2,
    const float* __restrict__ depth, const float* __restrict__ bias,
    const float* __restrict__ lfo_omega, const float* __restrict__ lfo_phi,
    const float* __restrict__ lfo_r_logit,
    const float* __restrict__ W_in, const float* __restrict__ b_in,
    const float* __restrict__ W_h, const float* __restrict__ b_h,
    const float* __restrict__ W_out, const float* __restrict__ b_out,
    const float* __restrict__ bq_dc, const float* __restrict__ bq_ff,
    const float* __restrict__ bq_fb,
    float* __restrict__ out, float* __restrict__ p_out,
    int N, int H, float S)
{
    __shared__ float hbufA[NROWS][16];
    __shared__ float hbufB[NROWS][16];
    __shared__ float rcb[NROWS][5];
    __shared__ float rcd[NROWS][4];

    const int lane = threadIdx.x;
    const int n0b  = blockIdx.x * BSPAN;

    // ---- phase 0: issue all x loads into registers (before phase 1) ----
    const int n0 = n0b + lane * LB;
    const int ns = n0 - WU;

    float4 xr[NQ];
    if (ns >= 0) {                               // all blocks except blk 0 lanes 0..2
        const float4* xv = (const float4*)(x + ns);
        #pragma unroll
        for (int q = 0; q < NQ; q++)
            xr[q] = xv[q];
    } else {
        #pragma unroll
        for (int q = 0; q < NQ; q++) {
            int np = ns + q * 4;
            xr[q].x = (np     >= 0) ? x[np]     : 0.0f;
            xr[q].y = (np + 1 >= 0) ? x[np + 1] : 0.0f;
            xr[q].z = (np + 2 >= 0) ? x[np + 2] : 0.0f;
            xr[q].w = (np + 3 >= 0) ? x[np + 3] : 0.0f;
        }
    }
    float x1 = (ns >= 1) ? x[ns - 1] : 0.0f;
    float x2 = (ns >= 2) ? x[ns - 2] : 0.0f;

    // scalar params issued early too (independent loads, overlap phase 1)
    float b0 = bq_dc[0], b1 = bq_ff[0], b2 = bq_ff[1];
    float fb0 = bq_fb[0], fb1 = bq_fb[1];
    float g = g1[0];

    // ---- phase 1: cooperative hop rows --------------------------------
    int i0start = (int)floorf((float)(n0b - WU) * S);
    i0start = min(max(i0start, 0), H - 2);

    {
        const int row = lane >> 3;       // 0..7
        const int u   = lane & 7;        // 2 units per lane: u, u+8
        const int t_r = min(i0start + row, H - 1);
        const float tf = (float)t_r;

        float rsig = 1.0f / (1.0f + expf(-lfo_r_logit[0]));
        float ph = lfo_omega[0] * tf + lfo_phi[0];
        float rt = powf(rsig, tf);
        float l0 = rt * cosf(ph);
        float l1 = rt * sinf(ph);

        // input layer
        #pragma unroll
        for (int jj = 0; jj < 2; jj++) {
            int j = u + jj * 8;
            hbufA[row][j] = tanhf(l0 * W_in[j] + l1 * W_in[16 + j] + b_in[j]);
        }
        __syncthreads();
        // hidden layer 0: A -> B
        #pragma unroll
        for (int jj = 0; jj < 2; jj++) {
            int j = u + jj * 8;
            float s = b_h[j];
            #pragma unroll
            for (int kk = 0; kk < 16; kk++)
                s += hbufA[row][kk] * W_h[kk * 16 + j];
            hbufB[row][j] = tanhf(s);
        }
        __syncthreads();
        // hidden layer 1: B -> A
        #pragma unroll
        for (int jj = 0; jj < 2; jj++) {
            int j = u + jj * 8;
            float s = b_h[16 + j];
            #pragma unroll
            for (int kk = 0; kk < 16; kk++)
                s += hbufB[row][kk] * W_h[(16 + kk) * 16 + j];
            hbufA[row][j] = tanhf(s);
        }
        __syncthreads();
        // output layer + coefficient rows (one lane per row)
        if (u == 0) {
            float s = b_out[0];
            #pragma unroll
            for (int kk = 0; kk < 16; kk++)
                s += hbufA[row][kk] * W_out[kk];
            float wsv = tanhf(s);
            float d = bias[0] + depth[0] * 0.5f * (1.0f + wsv);
            float td = tanf(d);
            float p = tanhf((1.0f - td) / (1.0f + td));
            p_out[t_r] = p;    // duplicate writes across blocks are identical
            float p2 = p * p, p3 = p2 * p, p4 = p2 * p2;
            float bap[5] = { p4, -4.0f * p3, 6.0f * p2, -4.0f * p, 1.0f };
            float aap[5] = { 1.0f, -4.0f * p, 6.0f * p2, -4.0f * p3, p4 };
            float ag2 = fabsf(g2[0]);
            float inv = 1.0f / (aap[0] - ag2 * bap[0]);
            #pragma unroll
            for (int m = 0; m < 5; m++) {
                float dm = aap[m] - ag2 * bap[m];
                rcb[row][m] = bap[m] * inv;
                if (m >= 1) rcd[row][m - 1] = dm * inv;
            }
        }
        __syncthreads();
    }

    // ---- phase 2: per-thread fused recurrence -------------------------
    float a1 = 2.0f * tanhf(fb0);
    float aa = fabsf(a1);
    float a2 = ((2.0f - aa) * tanhf(fb1) + aa) * 0.5f;

    int i0a = (int)floorf((float)ns * S);
    i0a = min(max(i0a, 0), H - 2);
    int rel = i0a - i0start;             // 0..3 by construction
    float i0af = (float)i0a;

    float Ab[5], sAb[5], sDb[5];
    float Ad[4], sAd[4], sDd[4];
    #pragma unroll
    for (int m = 0; m < 5; m++) {
        float lo = rcb[rel][m], mi = rcb[rel + 1][m], hi = rcb[rel + 2][m];
        Ab[m] = lo; sAb[m] = mi - lo; sDb[m] = (hi - mi) - (mi - lo);
    }
    #pragma unroll
    for (int m = 0; m < 4; m++) {
        float lo = rcd[rel][m], mi = rcd[rel + 1][m], hi = rcd[rel + 2][m];
        Ad[m] = lo; sAd[m] = mi - lo; sDd[m] = (hi - mi) - (mi - lo);
    }

    float y1 = 0, y2 = 0, y3 = 0, y4 = 0;      // biquad output history
    float z0 = 0, z1 = 0, z2 = 0, z3 = 0;      // LPC output history

    float4* ov = (float4*)(out + n0);

    #pragma unroll
    for (int q = 0; q < NQ; q++) {
        int np = ns + q * 4;
        float xs[4] = { xr[q].x, xr[q].y, xr[q].z, xr[q].w };
        float os[4];
        #pragma unroll
        for (int m = 0; m < 4; m++) {
            int n = np + m;
            float pos = (float)n * S;           // matches reference arange*S
            float fr0 = pos - i0af;
            float tr  = fmaxf(fr0 - 1.0f, 0.0f);
            float cbv[5], cdv[4];
            #pragma unroll
            for (int mm = 0; mm < 5; mm++)
                cbv[mm] = fmaf(tr, sDb[mm], fmaf(fr0, sAb[mm], Ab[mm]));
            #pragma unroll
            for (int mm = 0; mm < 4; mm++)
                cdv[mm] = fmaf(tr, sDd[mm], fmaf(fr0, sAd[mm], Ad[mm]));
            float x0 = xs[m];
            float v   = fmaf(b0, x0, fmaf(b1, x1, b2 * x2));
            float ybq = v - fmaf(a1, y1, a2 * y2);
            float v2  = fmaf(cbv[0], ybq, fmaf(cbv[1], y1,
                        fmaf(cbv[2], y2, fmaf(cbv[3], y3, cbv[4] * y4))));
            float yz  = v2 - fmaf(cdv[0], z0, fmaf(cdv[1], z1,
                        fmaf(cdv[2], z2, cdv[3] * z3)));
            os[m] = fmaf(g, ybq, yz);
            y4 = y3; y3 = y2; y2 = y1; y1 = ybq;
            x2 = x1; x1 = x0;
            z3 = z2; z2 = z1; z1 = z0; z0 = yz;
        }
        if (q >= WU / 4)
            ov[q - WU / 4] = make_float4(os[0], os[1], os[2], os[3]);
    }
}

// ---------------------------------------------------------------------------
// Launch
// ---------------------------------------------------------------------------
extern "C" void kernel_launch(void* const* d_in, const int* in_sizes, int n_in,
                              void* d_out, int out_size, void* d_ws, size_t ws_size,
                              hipStream_t stream)
{
    const float* x        = (const float*)d_in[0];
    const float* g1       = (const float*)d_in[1];
    const float* g2       = (const float*)d_in[2];
    const float* depth    = (const float*)d_in[3];
    const float* bias     = (const float*)d_in[4];
    const float* lfo_omega= (const float*)d_in[5];
    const float* lfo_phi  = (const float*)d_in[6];
    const float* lfo_r    = (const float*)d_in[7];
    const float* W_in     = (const float*)d_in[8];
    const float* b_in     = (const float*)d_in[9];
    const float* W_h      = (const float*)d_in[10];
    const float* b_h      = (const float*)d_in[11];
    const float* W_out    = (const float*)d_in[12];
    const float* b_out    = (const float*)d_in[13];
    const float* bq_dc    = (const float*)d_in[14];
    const float* bq_ff    = (const float*)d_in[15];
    const float* bq_fb    = (const float*)d_in[16];

    int N = in_sizes[0];
    int H = N / HOPSZ + 1;
    int nblocks = N / BSPAN;                 // 1024 for N = 2^20
    float S = (float)((double)(H - 1) / (double)(N - 1));

    float* outy = (float*)d_out;
    float* outp = outy + N;

    k_fused<<<nblocks, TPB, 0, stream>>>(
        x, g1, g2, depth, bias, lfo_omega, lfo_phi, lfo_r,
        W_in, b_in, W_h, b_h, W_out, b_out,
        bq_dc, bq_ff, bq_fb,
        outy, outp, N, H, S);
}

// Round 2
// 98.753 us; speedup vs baseline: 1.0149x; 1.0149x over previous
//
#include <hip/hip_runtime.h>
#include <math.h>

#define HOPSZ 551
#define LB   8             // output samples per thread (halved: 2 waves/SIMD)
#define WU   48            // warm-up samples (C(51,3)*p_max^48 ~ 2.7e-3 envelope)
#define SPAN (LB + WU)     // 56 samples processed per thread
#define TPB  64            // one wave per block
#define BSPAN (TPB * LB)   // 512 output samples per block
#define NROWS 8            // coefficient rows cached per block (need <= 4)
#define NQ   (SPAN / 4)    // 14 float4 loads per thread

// ---------------------------------------------------------------------------
// Single fused kernel:
//   phase 0: issue ALL x loads (14 x float4 + 2 history scalars) into
//     registers up front, so HBM latency overlaps phase-1 compute.
//   phase 1 (cooperative, one wave): compute NROWS hop-coefficient rows
//     (LFO -> 16-wide MLP -> p -> allpass cb[5]/cd[4]) into LDS; write p_out.
//   phase 2 (per-thread): warm-up + fused biquad -> TV-FIR -> LPC -> output,
//     entirely from registers.
// Exact piecewise-linear coeff interp: c(pos) = A + fr0*sA + relu(fr0-1)*sD,
// fr0 = pos - i0a; thread span (56 samples ~ 0.10 hop) crosses <= 1 knot.
// LB=8: grid 2048 blocks -> 2 waves/SIMD for cross-wave latency hiding.
// ---------------------------------------------------------------------------
__global__ __launch_bounds__(TPB) void k_fused(
    const float* __restrict__ x,
    const float* __restrict__ g1, const float* __restrict__ g2,
    const float* __restrict__ depth, const float* __restrict__ bias,
    const float* __restrict__ lfo_omega, const float* __restrict__ lfo_phi,
    const float* __restrict__ lfo_r_logit,
    const float* __restrict__ W_in, const float* __restrict__ b_in,
    const float* __restrict__ W_h, const float* __restrict__ b_h,
    const float* __restrict__ W_out, const float* __restrict__ b_out,
    const float* __restrict__ bq_dc, const float* __restrict__ bq_ff,
    const float* __restrict__ bq_fb,
    float* __restrict__ out, float* __restrict__ p_out,
    int N, int H, float S)
{
    __shared__ float hbufA[NROWS][16];
    __shared__ float hbufB[NROWS][16];
    __shared__ float rcb[NROWS][5];
    __shared__ float rcd[NROWS][4];

    const int lane = threadIdx.x;
    const int n0b  = blockIdx.x * BSPAN;

    // ---- phase 0: issue all x loads into registers (before phase 1) ----
    const int n0 = n0b + lane * LB;
    const int ns = n0 - WU;

    float4 xr[NQ];
    if (ns >= 0) {                               // all but block 0 lanes 0..5
        const float4* xv = (const float4*)(x + ns);
        #pragma unroll
        for (int q = 0; q < NQ; q++)
            xr[q] = xv[q];
    } else {
        #pragma unroll
        for (int q = 0; q < NQ; q++) {
            int np = ns + q * 4;
            xr[q].x = (np     >= 0) ? x[np]     : 0.0f;
            xr[q].y = (np + 1 >= 0) ? x[np + 1] : 0.0f;
            xr[q].z = (np + 2 >= 0) ? x[np + 2] : 0.0f;
            xr[q].w = (np + 3 >= 0) ? x[np + 3] : 0.0f;
        }
    }
    float x1 = (ns >= 1) ? x[ns - 1] : 0.0f;
    float x2 = (ns >= 2) ? x[ns - 2] : 0.0f;

    // scalar params issued early too (independent loads, overlap phase 1)
    float b0 = bq_dc[0], b1 = bq_ff[0], b2 = bq_ff[1];
    float fb0 = bq_fb[0], fb1 = bq_fb[1];
    float g = g1[0];

    // ---- phase 1: cooperative hop rows --------------------------------
    int i0start = (int)floorf((float)(n0b - WU) * S);
    i0start = min(max(i0start, 0), H - 2);

    {
        const int row = lane >> 3;       // 0..7
        const int u   = lane & 7;        // 2 units per lane: u, u+8
        const int t_r = min(i0start + row, H - 1);
        const float tf = (float)t_r;

        float rsig = 1.0f / (1.0f + expf(-lfo_r_logit[0]));
        float ph = lfo_omega[0] * tf + lfo_phi[0];
        float rt = powf(rsig, tf);
        float l0 = rt * cosf(ph);
        float l1 = rt * sinf(ph);

        // input layer
        #pragma unroll
        for (int jj = 0; jj < 2; jj++) {
            int j = u + jj * 8;
            hbufA[row][j] = tanhf(l0 * W_in[j] + l1 * W_in[16 + j] + b_in[j]);
        }
        __syncthreads();
        // hidden layer 0: A -> B
        #pragma unroll
        for (int jj = 0; jj < 2; jj++) {
            int j = u + jj * 8;
            float s = b_h[j];
            #pragma unroll
            for (int kk = 0; kk < 16; kk++)
                s += hbufA[row][kk] * W_h[kk * 16 + j];
            hbufB[row][j] = tanhf(s);
        }
        __syncthreads();
        // hidden layer 1: B -> A
        #pragma unroll
        for (int jj = 0; jj < 2; jj++) {
            int j = u + jj * 8;
            float s = b_h[16 + j];
            #pragma unroll
            for (int kk = 0; kk < 16; kk++)
                s += hbufB[row][kk] * W_h[(16 + kk) * 16 + j];
            hbufA[row][j] = tanhf(s);
        }
        __syncthreads();
        // output layer + coefficient rows (one lane per row)
        if (u == 0) {
            float s = b_out[0];
            #pragma unroll
            for (int kk = 0; kk < 16; kk++)
                s += hbufA[row][kk] * W_out[kk];
            float wsv = tanhf(s);
            float d = bias[0] + depth[0] * 0.5f * (1.0f + wsv);
            float td = tanf(d);
            float p = tanhf((1.0f - td) / (1.0f + td));
            p_out[t_r] = p;    // duplicate writes across blocks are identical
            float p2 = p * p, p3 = p2 * p, p4 = p2 * p2;
            float bap[5] = { p4, -4.0f * p3, 6.0f * p2, -4.0f * p, 1.0f };
            float aap[5] = { 1.0f, -4.0f * p, 6.0f * p2, -4.0f * p3, p4 };
            float ag2 = fabsf(g2[0]);
            float inv = 1.0f / (aap[0] - ag2 * bap[0]);
            #pragma unroll
            for (int m = 0; m < 5; m++) {
                float dm = aap[m] - ag2 * bap[m];
                rcb[row][m] = bap[m] * inv;
                if (m >= 1) rcd[row][m - 1] = dm * inv;
            }
        }
        __syncthreads();
    }

    // ---- phase 2: per-thread fused recurrence -------------------------
    float a1 = 2.0f * tanhf(fb0);
    float aa = fabsf(a1);
    float a2 = ((2.0f - aa) * tanhf(fb1) + aa) * 0.5f;

    int i0a = (int)floorf((float)ns * S);
    i0a = min(max(i0a, 0), H - 2);
    int rel = i0a - i0start;             // 0..2 by construction
    float i0af = (float)i0a;

    float Ab[5], sAb[5], sDb[5];
    float Ad[4], sAd[4], sDd[4];
    #pragma unroll
    for (int m = 0; m < 5; m++) {
        float lo = rcb[rel][m], mi = rcb[rel + 1][m], hi = rcb[rel + 2][m];
        Ab[m] = lo; sAb[m] = mi - lo; sDb[m] = (hi - mi) - (mi - lo);
    }
    #pragma unroll
    for (int m = 0; m < 4; m++) {
        float lo = rcd[rel][m], mi = rcd[rel + 1][m], hi = rcd[rel + 2][m];
        Ad[m] = lo; sAd[m] = mi - lo; sDd[m] = (hi - mi) - (mi - lo);
    }

    float y1 = 0, y2 = 0, y3 = 0, y4 = 0;      // biquad output history
    float z0 = 0, z1 = 0, z2 = 0, z3 = 0;      // LPC output history

    float4* ov = (float4*)(out + n0);

    #pragma unroll
    for (int q = 0; q < NQ; q++) {
        int np = ns + q * 4;
        float xs[4] = { xr[q].x, xr[q].y, xr[q].z, xr[q].w };
        float os[4];
        #pragma unroll
        for (int m = 0; m < 4; m++) {
            int n = np + m;
            float pos = (float)n * S;           // matches reference arange*S
            float fr0 = pos - i0af;
            float tr  = fmaxf(fr0 - 1.0f, 0.0f);
            float cbv[5], cdv[4];
            #pragma unroll
            for (int mm = 0; mm < 5; mm++)
                cbv[mm] = fmaf(tr, sDb[mm], fmaf(fr0, sAb[mm], Ab[mm]));
            #pragma unroll
            for (int mm = 0; mm < 4; mm++)
                cdv[mm] = fmaf(tr, sDd[mm], fmaf(fr0, sAd[mm], Ad[mm]));
            float x0 = xs[m];
            float v   = fmaf(b0, x0, fmaf(b1, x1, b2 * x2));
            float ybq = v - fmaf(a1, y1, a2 * y2);
            float v2  = fmaf(cbv[0], ybq, fmaf(cbv[1], y1,
                        fmaf(cbv[2], y2, fmaf(cbv[3], y3, cbv[4] * y4))));
            float yz  = v2 - fmaf(cdv[0], z0, fmaf(cdv[1], z1,
                        fmaf(cdv[2], z2, cdv[3] * z3)));
            os[m] = fmaf(g, ybq, yz);
            y4 = y3; y3 = y2; y2 = y1; y1 = ybq;
            x2 = x1; x1 = x0;
            z3 = z2; z2 = z1; z1 = z0; z0 = yz;
        }
        if (q >= WU / 4)
            ov[q - WU / 4] = make_float4(os[0], os[1], os[2], os[3]);
    }
}

// ---------------------------------------------------------------------------
// Launch
// ---------------------------------------------------------------------------
extern "C" void kernel_launch(void* const* d_in, const int* in_sizes, int n_in,
                              void* d_out, int out_size, void* d_ws, size_t ws_size,
                              hipStream_t stream)
{
    const float* x        = (const float*)d_in[0];
    const float* g1       = (const float*)d_in[1];
    const float* g2       = (const float*)d_in[2];
    const float* depth    = (const float*)d_in[3];
    const float* bias     = (const float*)d_in[4];
    const float* lfo_omega= (const float*)d_in[5];
    const float* lfo_phi  = (const float*)d_in[6];
    const float* lfo_r    = (const float*)d_in[7];
    const float* W_in     = (const float*)d_in[8];
    const float* b_in     = (const float*)d_in[9];
    const float* W_h      = (const float*)d_in[10];
    const float* b_h      = (const float*)d_in[11];
    const float* W_out    = (const float*)d_in[12];
    const float* b_out    = (const float*)d_in[13];
    const float* bq_dc    = (const float*)d_in[14];
    const float* bq_ff    = (const float*)d_in[15];
    const float* bq_fb    = (const float*)d_in[16];

    int N = in_sizes[0];
    int H = N / HOPSZ + 1;
    int nblocks = N / BSPAN;                 // 2048 for N = 2^20
    float S = (float)((double)(H - 1) / (double)(N - 1));

    float* outy = (float*)d_out;
    float* outp = outy + N;

    k_fused<<<nblocks, TPB, 0, stream>>>(
        x, g1, g2, depth, bias, lfo_omega, lfo_phi, lfo_r,
        W_in, b_in, W_h, b_h, W_out, b_out,
        bq_dc, bq_ff, bq_fb,
        outy, outp, N, H, S);
}